// Round 7
// baseline (516.486 us; speedup 1.0000x reference)
//
#include <hip/hip_runtime.h>
#include <hip/hip_bf16.h>

#define N_NODES 100000
#define E_NUM   1600000
#define IN_DIM  128
#define HID     64
#define NCLS    40
#define NBUCK   782      // ceil(N_NODES/128); bucket b owns nodes [b*128, b*128+128)
#define TILE_E  8192
#define NTILE   196      // ceil(E_NUM / TILE_E)

// ---------------- K1: H = relu(x @ W_in + b_in) ----------------------------
__global__ __launch_bounds__(256) void k_in_gemm(
    const float* __restrict__ x, const float* __restrict__ W,
    const float* __restrict__ b, float* __restrict__ H)
{
    __shared__ float sW[IN_DIM * HID];   // 32 KB, [k][j]
    __shared__ float sx[16][IN_DIM];     // 8 KB
    const int t = threadIdx.x;
    const int lane = t & 63;
    const int w    = t >> 6;
    for (int i = t; i < IN_DIM * HID; i += 256) sW[i] = W[i];
    const int row0 = blockIdx.x * 16;    // N_NODES = 16 * 6250
    const float4* xsrc = (const float4*)(x + (size_t)row0 * IN_DIM);
    for (int i = t; i < 16 * IN_DIM / 4; i += 256) ((float4*)sx)[i] = xsrc[i];
    __syncthreads();

    const float bias = b[lane];
    float a0 = bias, a1 = bias, a2 = bias, a3 = bias;
    #pragma unroll
    for (int kk = 0; kk < IN_DIM / 4; ++kk) {
        const int k0 = kk * 4;
        const float w0 = sW[(k0    ) * HID + lane];
        const float w1 = sW[(k0 + 1) * HID + lane];
        const float w2 = sW[(k0 + 2) * HID + lane];
        const float w3 = sW[(k0 + 3) * HID + lane];
        const float4 r0 = *(const float4*)&sx[w     ][k0];
        const float4 r1 = *(const float4*)&sx[w +  4][k0];
        const float4 r2 = *(const float4*)&sx[w +  8][k0];
        const float4 r3 = *(const float4*)&sx[w + 12][k0];
        a0 += r0.x*w0 + r0.y*w1 + r0.z*w2 + r0.w*w3;
        a1 += r1.x*w0 + r1.y*w1 + r1.z*w2 + r1.w*w3;
        a2 += r2.x*w0 + r2.y*w1 + r2.z*w2 + r2.w*w3;
        a3 += r3.x*w0 + r3.y*w1 + r3.z*w2 + r3.w*w3;
    }
    const size_t base = (size_t)row0 * HID + lane;
    H[base +  w       * HID] = fmaxf(a0, 0.f);
    H[base + (w +  4) * HID] = fmaxf(a1, 0.f);
    H[base + (w +  8) * HID] = fmaxf(a2, 0.f);
    H[base + (w + 12) * HID] = fmaxf(a3, 0.f);
}

// ---------------- bucket partition + in-bucket CSR build -------------------
__global__ void k_zero_hist(int* __restrict__ h) {
    int i = blockIdx.x * 256 + threadIdx.x;
    if (i < NBUCK) h[i] = 0;
}

__global__ __launch_bounds__(256) void k_hist(
    const int* __restrict__ ei, int* __restrict__ hist)
{
    __shared__ int lh[NBUCK];
    const int t = threadIdx.x;
    for (int i = t; i < NBUCK; i += 256) lh[i] = 0;
    __syncthreads();
    const int e0 = blockIdx.x * TILE_E;
    for (int k = 0; k < TILE_E; k += 256) {
        int e = e0 + k + t;
        if (e < E_NUM) atomicAdd(&lh[ei[E_NUM + e] >> 7], 1);
    }
    __syncthreads();
    for (int i = t; i < NBUCK; i += 256) if (lh[i]) atomicAdd(&hist[i], lh[i]);
}

__global__ __launch_bounds__(1024) void k_scan(
    const int* __restrict__ hist, int* __restrict__ base, int* __restrict__ cursor)
{
    __shared__ int s[1024];
    const int t = threadIdx.x;
    const int v = (t < NBUCK) ? hist[t] : 0;
    s[t] = v; __syncthreads();
    for (int off = 1; off < 1024; off <<= 1) {
        int a = (t >= off) ? s[t - off] : 0;
        __syncthreads(); s[t] += a; __syncthreads();
    }
    if (t < NBUCK) { int ex = s[t] - v; base[t] = ex; cursor[t] = ex; }
    if (t == NBUCK) base[t] = E_NUM;
}

// tile-private chunk reservation -> block-exclusive contiguous writes
__global__ __launch_bounds__(256) void k_part(
    const int* __restrict__ ei, int* __restrict__ cursor, int* __restrict__ pairs)
{
    __shared__ int lh[NBUCK];
    __shared__ int lbase[NBUCK];
    __shared__ int lcnt[NBUCK];
    const int t = threadIdx.x;
    for (int i = t; i < NBUCK; i += 256) { lh[i] = 0; lcnt[i] = 0; }
    __syncthreads();
    const int e0 = blockIdx.x * TILE_E;
    for (int k = 0; k < TILE_E; k += 256) {
        int e = e0 + k + t;
        if (e < E_NUM) atomicAdd(&lh[ei[E_NUM + e] >> 7], 1);
    }
    __syncthreads();
    for (int i = t; i < NBUCK; i += 256)
        lbase[i] = lh[i] ? atomicAdd(&cursor[i], lh[i]) : 0;
    __syncthreads();
    for (int k = 0; k < TILE_E; k += 256) {
        int e = e0 + k + t;
        if (e < E_NUM) {
            int src = ei[e];
            int dst = ei[E_NUM + e];
            int b   = dst >> 7;
            int r   = atomicAdd(&lcnt[b], 1);
            pairs[lbase[b] + r] = (src << 7) | (dst & 127);  // src < 2^17, fits
        }
    }
}

// one block per bucket: exact per-node CSR, writes stay in block-owned region
__global__ __launch_bounds__(256) void k_bsort(
    const int* __restrict__ base, const int* __restrict__ pairs,
    int* __restrict__ srcs, int* __restrict__ row_start)
{
    __shared__ int cnt[128];
    __shared__ int sc[128];
    __shared__ int cur[128];
    const int t = threadIdx.x;
    const int b = blockIdx.x;
    const int beg = base[b], end = base[b + 1];
    if (t < 128) cnt[t] = 0;
    __syncthreads();
    for (int i = beg + t; i < end; i += 256)
        atomicAdd(&cnt[pairs[i] & 127], 1);
    __syncthreads();
    if (t < 128) sc[t] = cnt[t];
    __syncthreads();
    for (int off = 1; off < 128; off <<= 1) {
        int a = (t < 128 && t >= off) ? sc[t - off] : 0;
        __syncthreads();
        if (t < 128) sc[t] += a;
        __syncthreads();
    }
    const int node0 = b << 7;
    if (t < 128) {
        int ex = sc[t] - cnt[t];      // exclusive prefix within bucket
        cur[t] = ex;
        if (node0 + t < N_NODES) row_start[node0 + t] = beg + ex;
    }
    if (b == 0 && t == 0) row_start[N_NODES] = E_NUM;
    __syncthreads();
    for (int i = beg + t; i < end; i += 256) {
        int p = pairs[i];
        int r = atomicAdd(&cur[p & 127], 1);
        srcs[beg + r] = p >> 7;
    }
}

// ------- fused: U = H[n] + sum H[src]  then  Hout = relu(U @ W + b) --------
// Gather v2: coalesced 64-wide srcs batch + __shfl broadcast; half-wave
// float2 pairing (one 512 B VMEM fetches TWO H rows); __shfl_xor(32) combine.
__global__ __launch_bounds__(256) void k_gather_gemm(
    const int* __restrict__ row_start, const int* __restrict__ srcs,
    const float* __restrict__ Hin, const float* __restrict__ Wl,
    const float* __restrict__ bl, float* __restrict__ Hout)
{
    __shared__ float sW[HID * HID];   // 16 KB, [k][j]
    __shared__ float su[16][HID];     // 4 KB
    const int t = threadIdx.x;
    for (int i = t; i < HID * HID; i += 256) sW[i] = Wl[i];
    const int lane = t & 63;
    const int w    = t >> 6;
    const int half = lane >> 5;       // 0: even edges, 1: odd edges
    const int fl   = lane & 31;       // this lane's feature pair = {2fl, 2fl+1}
    const int row0 = blockIdx.x * 16;

    for (int q = 0; q < 4; ++q) {
        const int n   = row0 + (w << 2) + q;
        int beg = row_start[n];
        int cnt = row_start[n + 1] - beg;
        float ax = 0.f, ay = 0.f;
        while (cnt > 0) {
            const int rem = (cnt < 64) ? cnt : 64;
            const int sb  = (lane < rem) ? srcs[beg + lane] : 0;
            const int npair = (rem + 1) >> 1;
            for (int p = 0; p < npair; p += 4) {
                #pragma unroll
                for (int k2 = 0; k2 < 4; ++k2) {
                    const int e  = 2 * (p + k2) + half;
                    const int sv = __shfl(sb, e & 63, 64);
                    const float2 v = *((const float2*)(Hin + (size_t)sv * HID) + fl);
                    if (e < rem) { ax += v.x; ay += v.y; }
                }
            }
            beg += rem; cnt -= rem;
        }
        // combine the two half-wave partial sums
        ax += __shfl_xor(ax, 32, 64);
        ay += __shfl_xor(ay, 32, 64);
        // self term
        const float2 self = *((const float2*)(Hin + (size_t)n * HID) + fl);
        ax += self.x; ay += self.y;
        if (half == 0) {
            float2 r; r.x = ax; r.y = ay;
            *((float2*)&su[(w << 2) + q][0] + fl) = r;
        }
    }
    __syncthreads();

    const float bias = bl[lane];
    float a0 = bias, a1 = bias, a2 = bias, a3 = bias;
    #pragma unroll
    for (int kk = 0; kk < HID / 4; ++kk) {
        const int k0 = kk * 4;
        const float w0 = sW[(k0    ) * HID + lane];
        const float w1 = sW[(k0 + 1) * HID + lane];
        const float w2 = sW[(k0 + 2) * HID + lane];
        const float w3 = sW[(k0 + 3) * HID + lane];
        const float4 r0 = *(const float4*)&su[w     ][k0];
        const float4 r1 = *(const float4*)&su[w +  4][k0];
        const float4 r2 = *(const float4*)&su[w +  8][k0];
        const float4 r3 = *(const float4*)&su[w + 12][k0];
        a0 += r0.x*w0 + r0.y*w1 + r0.z*w2 + r0.w*w3;
        a1 += r1.x*w0 + r1.y*w1 + r1.z*w2 + r1.w*w3;
        a2 += r2.x*w0 + r2.y*w1 + r2.z*w2 + r2.w*w3;
        a3 += r3.x*w0 + r3.y*w1 + r3.z*w2 + r3.w*w3;
    }
    const size_t ob = (size_t)row0 * HID + lane;
    Hout[ob +  w       * HID] = fmaxf(a0, 0.f);
    Hout[ob + (w +  4) * HID] = fmaxf(a1, 0.f);
    Hout[ob + (w +  8) * HID] = fmaxf(a2, 0.f);
    Hout[ob + (w + 12) * HID] = fmaxf(a3, 0.f);
}

// ---------------- classifier ----------------------------------------------
__global__ __launch_bounds__(256) void k_cls(
    const float* __restrict__ Wc, const float* __restrict__ bc,
    const float* __restrict__ H, float* __restrict__ out)
{
    __shared__ float sW[HID * NCLS];  // 10 KB, [k][j]
    __shared__ float su[16][HID];
    const int t = threadIdx.x;
    const int lane = t & 63;
    const int w    = t >> 6;
    for (int i = t; i < HID * NCLS; i += 256) sW[i] = Wc[i];
    const int row0 = blockIdx.x * 16;
    const float4* usrc = (const float4*)(H + (size_t)row0 * HID);
    for (int i = t; i < 16 * HID / 4; i += 256) ((float4*)su)[i] = usrc[i];
    __syncthreads();

    if (lane >= NCLS) return;
    const float bias = bc[lane];
    float a0 = bias, a1 = bias, a2 = bias, a3 = bias;
    #pragma unroll
    for (int kk = 0; kk < HID / 4; ++kk) {
        const int k0 = kk * 4;
        const float w0 = sW[(k0    ) * NCLS + lane];
        const float w1 = sW[(k0 + 1) * NCLS + lane];
        const float w2 = sW[(k0 + 2) * NCLS + lane];
        const float w3 = sW[(k0 + 3) * NCLS + lane];
        const float4 r0 = *(const float4*)&su[w     ][k0];
        const float4 r1 = *(const float4*)&su[w +  4][k0];
        const float4 r2 = *(const float4*)&su[w +  8][k0];
        const float4 r3 = *(const float4*)&su[w + 12][k0];
        a0 += r0.x*w0 + r0.y*w1 + r0.z*w2 + r0.w*w3;
        a1 += r1.x*w0 + r1.y*w1 + r1.z*w2 + r1.w*w3;
        a2 += r2.x*w0 + r2.y*w1 + r2.z*w2 + r2.w*w3;
        a3 += r3.x*w0 + r3.y*w1 + r3.z*w2 + r3.w*w3;
    }
    const size_t base = (size_t)row0 * NCLS + lane;
    out[base +  w       * NCLS] = a0;
    out[base + (w +  4) * NCLS] = a1;
    out[base + (w +  8) * NCLS] = a2;
    out[base + (w + 12) * NCLS] = a3;
}

extern "C" void kernel_launch(void* const* d_in, const int* in_sizes, int n_in,
                              void* d_out, int out_size, void* d_ws, size_t ws_size,
                              hipStream_t stream)
{
    const float* x        = (const float*)d_in[0];
    const int*   ei       = (const int*)  d_in[1];
    const float* W_in     = (const float*)d_in[2];
    const float* b_in     = (const float*)d_in[3];
    const float* W_layers = (const float*)d_in[4];
    const float* b_layers = (const float*)d_in[5];
    const float* W_cls    = (const float*)d_in[6];
    const float* b_cls    = (const float*)d_in[7];
    float* out = (float*)d_out;

    // ws: two 25.6 MB node-feature buffers (ping-pong)
    float* H0 = (float*)d_ws;
    float* H1 = H0 + (size_t)N_NODES * HID;

    // build scratch lives in the x input buffer (51.2 MB = 12.8M ints), used
    // only AFTER k_in_gemm consumed x (stream-ordered). Harness restores
    // inputs from pristine before every launch, so clobbering is sanctioned.
    int* xb        = (int*)d_in[0];
    int* pairs     = xb;                          // 1.6M ints
    int* srcs      = xb + E_NUM;                  // 1.6M ints
    int* row_start = xb + 2 * E_NUM;              // 100001 ints
    int* hist      = xb + 2 * E_NUM + 100064;     // 782
    int* base      = hist + 1024;                 // 783
    int* cursor    = base + 1024;                 // 782

    const int gemm_blocks = N_NODES / 16;         // 6250

    k_in_gemm  <<<gemm_blocks, 256, 0, stream>>>(x, W_in, b_in, H0);

    k_zero_hist<<<4, 256, 0, stream>>>(hist);
    k_hist     <<<NTILE, 256, 0, stream>>>(ei, hist);
    k_scan     <<<1, 1024, 0, stream>>>(hist, base, cursor);
    k_part     <<<NTILE, 256, 0, stream>>>(ei, cursor, pairs);
    k_bsort    <<<NBUCK, 256, 0, stream>>>(base, pairs, srcs, row_start);

    float* Hi = H0; float* Ho = H1;
    for (int i = 0; i < 3; ++i) {
        k_gather_gemm<<<gemm_blocks, 256, 0, stream>>>(
            row_start, srcs, Hi,
            W_layers + (size_t)i * HID * HID, b_layers + (size_t)i * HID, Ho);
        float* tmp = Hi; Hi = Ho; Ho = tmp;
    }
    k_cls<<<gemm_blocks, 256, 0, stream>>>(W_cls, b_cls, Hi, out);
}

// Round 8
// 435.080 us; speedup vs baseline: 1.1871x; 1.1871x over previous
//
#include <hip/hip_runtime.h>
#include <hip/hip_bf16.h>

#define N_NODES 100000
#define E_NUM   1600000
#define IN_DIM  128
#define HID     64
#define NCLS    40
#define NBUCK   782      // ceil(N_NODES/128); bucket b owns nodes [b*128, b*128+128)
#define TILE_E  8192
#define NTILE   196      // ceil(E_NUM / TILE_E)

// bf16 helpers: H rows are 64 x bf16 = 128 B, read as uint (2 feats / lane)
static __device__ __forceinline__ float bflo(unsigned u) {
    return __uint_as_float(u << 16);
}
static __device__ __forceinline__ float bfhi(unsigned u) {
    return __uint_as_float(u & 0xFFFF0000u);
}
static __device__ __forceinline__ unsigned short f2bf(float f) {
    unsigned u = __float_as_uint(f);
    u += 0x7FFFu + ((u >> 16) & 1u);     // round-to-nearest-even
    return (unsigned short)(u >> 16);
}

// ---------------- K1: Hbf = relu(x @ W_in + b_in) --------------------------
__global__ __launch_bounds__(256) void k_in_gemm(
    const float* __restrict__ x, const float* __restrict__ W,
    const float* __restrict__ b, unsigned short* __restrict__ H)
{
    __shared__ float sW[IN_DIM * HID];   // 32 KB, [k][j]
    __shared__ float sx[16][IN_DIM];     // 8 KB
    const int t = threadIdx.x;
    const int lane = t & 63;
    const int w    = t >> 6;
    for (int i = t; i < IN_DIM * HID; i += 256) sW[i] = W[i];
    const int row0 = blockIdx.x * 16;    // N_NODES = 16 * 6250
    const float4* xsrc = (const float4*)(x + (size_t)row0 * IN_DIM);
    for (int i = t; i < 16 * IN_DIM / 4; i += 256) ((float4*)sx)[i] = xsrc[i];
    __syncthreads();

    const float bias = b[lane];
    float a0 = bias, a1 = bias, a2 = bias, a3 = bias;
    #pragma unroll
    for (int kk = 0; kk < IN_DIM / 4; ++kk) {
        const int k0 = kk * 4;
        const float w0 = sW[(k0    ) * HID + lane];
        const float w1 = sW[(k0 + 1) * HID + lane];
        const float w2 = sW[(k0 + 2) * HID + lane];
        const float w3 = sW[(k0 + 3) * HID + lane];
        const float4 r0 = *(const float4*)&sx[w     ][k0];
        const float4 r1 = *(const float4*)&sx[w +  4][k0];
        const float4 r2 = *(const float4*)&sx[w +  8][k0];
        const float4 r3 = *(const float4*)&sx[w + 12][k0];
        a0 += r0.x*w0 + r0.y*w1 + r0.z*w2 + r0.w*w3;
        a1 += r1.x*w0 + r1.y*w1 + r1.z*w2 + r1.w*w3;
        a2 += r2.x*w0 + r2.y*w1 + r2.z*w2 + r2.w*w3;
        a3 += r3.x*w0 + r3.y*w1 + r3.z*w2 + r3.w*w3;
    }
    const size_t base = (size_t)row0 * HID + lane;
    H[base +  w       * HID] = f2bf(fmaxf(a0, 0.f));
    H[base + (w +  4) * HID] = f2bf(fmaxf(a1, 0.f));
    H[base + (w +  8) * HID] = f2bf(fmaxf(a2, 0.f));
    H[base + (w + 12) * HID] = f2bf(fmaxf(a3, 0.f));
}

// ---------------- bucket partition + in-bucket CSR build -------------------
__global__ void k_zero_hist(int* __restrict__ h) {
    int i = blockIdx.x * 256 + threadIdx.x;
    if (i < NBUCK) h[i] = 0;
}

__global__ __launch_bounds__(256) void k_hist(
    const int* __restrict__ ei, int* __restrict__ hist)
{
    __shared__ int lh[NBUCK];
    const int t = threadIdx.x;
    for (int i = t; i < NBUCK; i += 256) lh[i] = 0;
    __syncthreads();
    const int e0 = blockIdx.x * TILE_E;
    for (int k = 0; k < TILE_E; k += 256) {
        int e = e0 + k + t;
        if (e < E_NUM) atomicAdd(&lh[ei[E_NUM + e] >> 7], 1);
    }
    __syncthreads();
    for (int i = t; i < NBUCK; i += 256) if (lh[i]) atomicAdd(&hist[i], lh[i]);
}

__global__ __launch_bounds__(1024) void k_scan(
    const int* __restrict__ hist, int* __restrict__ base, int* __restrict__ cursor)
{
    __shared__ int s[1024];
    const int t = threadIdx.x;
    const int v = (t < NBUCK) ? hist[t] : 0;
    s[t] = v; __syncthreads();
    for (int off = 1; off < 1024; off <<= 1) {
        int a = (t >= off) ? s[t - off] : 0;
        __syncthreads(); s[t] += a; __syncthreads();
    }
    if (t < NBUCK) { int ex = s[t] - v; base[t] = ex; cursor[t] = ex; }
    if (t == NBUCK) base[t] = E_NUM;
}

// tile-private chunk reservation -> block-exclusive contiguous writes
__global__ __launch_bounds__(256) void k_part(
    const int* __restrict__ ei, int* __restrict__ cursor, int* __restrict__ pairs)
{
    __shared__ int lh[NBUCK];
    __shared__ int lbase[NBUCK];
    __shared__ int lcnt[NBUCK];
    const int t = threadIdx.x;
    for (int i = t; i < NBUCK; i += 256) { lh[i] = 0; lcnt[i] = 0; }
    __syncthreads();
    const int e0 = blockIdx.x * TILE_E;
    for (int k = 0; k < TILE_E; k += 256) {
        int e = e0 + k + t;
        if (e < E_NUM) atomicAdd(&lh[ei[E_NUM + e] >> 7], 1);
    }
    __syncthreads();
    for (int i = t; i < NBUCK; i += 256)
        lbase[i] = lh[i] ? atomicAdd(&cursor[i], lh[i]) : 0;
    __syncthreads();
    for (int k = 0; k < TILE_E; k += 256) {
        int e = e0 + k + t;
        if (e < E_NUM) {
            int src = ei[e];
            int dst = ei[E_NUM + e];
            int b   = dst >> 7;
            int r   = atomicAdd(&lcnt[b], 1);
            pairs[lbase[b] + r] = (src << 7) | (dst & 127);  // src < 2^17, fits
        }
    }
}

// one block per bucket: exact per-node CSR, writes stay in block-owned region
__global__ __launch_bounds__(256) void k_bsort(
    const int* __restrict__ base, const int* __restrict__ pairs,
    int* __restrict__ srcs, int* __restrict__ row_start)
{
    __shared__ int cnt[128];
    __shared__ int sc[128];
    __shared__ int cur[128];
    const int t = threadIdx.x;
    const int b = blockIdx.x;
    const int beg = base[b], end = base[b + 1];
    if (t < 128) cnt[t] = 0;
    __syncthreads();
    for (int i = beg + t; i < end; i += 256)
        atomicAdd(&cnt[pairs[i] & 127], 1);
    __syncthreads();
    if (t < 128) sc[t] = cnt[t];
    __syncthreads();
    for (int off = 1; off < 128; off <<= 1) {
        int a = (t < 128 && t >= off) ? sc[t - off] : 0;
        __syncthreads();
        if (t < 128) sc[t] += a;
        __syncthreads();
    }
    const int node0 = b << 7;
    if (t < 128) {
        int ex = sc[t] - cnt[t];      // exclusive prefix within bucket
        cur[t] = ex;
        if (node0 + t < N_NODES) row_start[node0 + t] = beg + ex;
    }
    if (b == 0 && t == 0) row_start[N_NODES] = E_NUM;
    __syncthreads();
    for (int i = beg + t; i < end; i += 256) {
        int p = pairs[i];
        int r = atomicAdd(&cur[p & 127], 1);
        srcs[beg + r] = p >> 7;
    }
}

// ------- fused: U = H[n] + sum H[src]  then  Hout = relu(U @ W + b) --------
// bf16 rows (128 B). Half-wave pairing: lanes 0-31 even edges, 32-63 odd;
// each lane loads one uint (2 bf16 feats) -> one VMEM fetches TWO rows.
// srcs loaded directly (uniform addr per half-wave); fp32 accumulate + GEMM.
__global__ __launch_bounds__(256) void k_gather_gemm(
    const int* __restrict__ row_start, const int* __restrict__ srcs,
    const unsigned short* __restrict__ Hin, const float* __restrict__ Wl,
    const float* __restrict__ bl, unsigned short* __restrict__ Hout)
{
    __shared__ float sW[HID * HID];   // 16 KB, [k][j]
    __shared__ float su[16][HID];     // 4 KB
    const int t = threadIdx.x;
    for (int i = t; i < HID * HID; i += 256) sW[i] = Wl[i];
    const int lane = t & 63;
    const int w    = t >> 6;
    const int half = lane >> 5;       // 0: even edges, 1: odd edges
    const int fl   = lane & 31;       // feature pair {2fl, 2fl+1}
    const int row0 = blockIdx.x * 16;

    for (int q = 0; q < 4; ++q) {
        const int n   = row0 + (w << 2) + q;
        const int beg = row_start[n];
        const int end = row_start[n + 1];
        float ax = 0.f, ay = 0.f;
        int i = beg + half;
        for (; i + 6 < end; i += 8) {             // edges i, i+2, i+4, i+6
            const int s0 = srcs[i], s1 = srcs[i + 2], s2 = srcs[i + 4], s3 = srcs[i + 6];
            const unsigned u0 = *(const unsigned*)(Hin + (size_t)s0 * HID + 2 * fl);
            const unsigned u1 = *(const unsigned*)(Hin + (size_t)s1 * HID + 2 * fl);
            const unsigned u2 = *(const unsigned*)(Hin + (size_t)s2 * HID + 2 * fl);
            const unsigned u3 = *(const unsigned*)(Hin + (size_t)s3 * HID + 2 * fl);
            ax += bflo(u0); ay += bfhi(u0);
            ax += bflo(u1); ay += bfhi(u1);
            ax += bflo(u2); ay += bfhi(u2);
            ax += bflo(u3); ay += bfhi(u3);
        }
        for (; i < end; i += 2) {
            const unsigned u = *(const unsigned*)(Hin + (size_t)srcs[i] * HID + 2 * fl);
            ax += bflo(u); ay += bfhi(u);
        }
        ax += __shfl_xor(ax, 32, 64);
        ay += __shfl_xor(ay, 32, 64);
        const unsigned us = *(const unsigned*)(Hin + (size_t)n * HID + 2 * fl);
        ax += bflo(us); ay += bfhi(us);
        if (half == 0) {
            float2 r; r.x = ax; r.y = ay;
            *((float2*)&su[(w << 2) + q][0] + fl) = r;
        }
    }
    __syncthreads();

    const float bias = bl[lane];
    float a0 = bias, a1 = bias, a2 = bias, a3 = bias;
    #pragma unroll
    for (int kk = 0; kk < HID / 4; ++kk) {
        const int k0 = kk * 4;
        const float w0 = sW[(k0    ) * HID + lane];
        const float w1 = sW[(k0 + 1) * HID + lane];
        const float w2 = sW[(k0 + 2) * HID + lane];
        const float w3 = sW[(k0 + 3) * HID + lane];
        const float4 r0 = *(const float4*)&su[w     ][k0];
        const float4 r1 = *(const float4*)&su[w +  4][k0];
        const float4 r2 = *(const float4*)&su[w +  8][k0];
        const float4 r3 = *(const float4*)&su[w + 12][k0];
        a0 += r0.x*w0 + r0.y*w1 + r0.z*w2 + r0.w*w3;
        a1 += r1.x*w0 + r1.y*w1 + r1.z*w2 + r1.w*w3;
        a2 += r2.x*w0 + r2.y*w1 + r2.z*w2 + r2.w*w3;
        a3 += r3.x*w0 + r3.y*w1 + r3.z*w2 + r3.w*w3;
    }
    const size_t ob = (size_t)row0 * HID + lane;
    Hout[ob +  w       * HID] = f2bf(fmaxf(a0, 0.f));
    Hout[ob + (w +  4) * HID] = f2bf(fmaxf(a1, 0.f));
    Hout[ob + (w +  8) * HID] = f2bf(fmaxf(a2, 0.f));
    Hout[ob + (w + 12) * HID] = f2bf(fmaxf(a3, 0.f));
}

// ---------------- classifier (reads bf16 H, fp32 out) ----------------------
__global__ __launch_bounds__(256) void k_cls(
    const float* __restrict__ Wc, const float* __restrict__ bc,
    const unsigned short* __restrict__ H, float* __restrict__ out)
{
    __shared__ float sW[HID * NCLS];  // 10 KB, [k][j]
    __shared__ float su[16][HID];
    const int t = threadIdx.x;
    const int lane = t & 63;
    const int w    = t >> 6;
    for (int i = t; i < HID * NCLS; i += 256) sW[i] = Wc[i];
    const int row0 = blockIdx.x * 16;
    // 16 rows x 64 bf16 = 256 uint2; thread t converts bf16[4t..4t+3]
    const uint2 v = ((const uint2*)(H + (size_t)row0 * HID))[t];
    ((float*)su)[4 * t    ] = bflo(v.x);
    ((float*)su)[4 * t + 1] = bfhi(v.x);
    ((float*)su)[4 * t + 2] = bflo(v.y);
    ((float*)su)[4 * t + 3] = bfhi(v.y);
    __syncthreads();

    if (lane >= NCLS) return;
    const float bias = bc[lane];
    float a0 = bias, a1 = bias, a2 = bias, a3 = bias;
    #pragma unroll
    for (int kk = 0; kk < HID / 4; ++kk) {
        const int k0 = kk * 4;
        const float w0 = sW[(k0    ) * NCLS + lane];
        const float w1 = sW[(k0 + 1) * NCLS + lane];
        const float w2 = sW[(k0 + 2) * NCLS + lane];
        const float w3 = sW[(k0 + 3) * NCLS + lane];
        const float4 r0 = *(const float4*)&su[w     ][k0];
        const float4 r1 = *(const float4*)&su[w +  4][k0];
        const float4 r2 = *(const float4*)&su[w +  8][k0];
        const float4 r3 = *(const float4*)&su[w + 12][k0];
        a0 += r0.x*w0 + r0.y*w1 + r0.z*w2 + r0.w*w3;
        a1 += r1.x*w0 + r1.y*w1 + r1.z*w2 + r1.w*w3;
        a2 += r2.x*w0 + r2.y*w1 + r2.z*w2 + r2.w*w3;
        a3 += r3.x*w0 + r3.y*w1 + r3.z*w2 + r3.w*w3;
    }
    const size_t base = (size_t)row0 * NCLS + lane;
    out[base +  w       * NCLS] = a0;
    out[base + (w +  4) * NCLS] = a1;
    out[base + (w +  8) * NCLS] = a2;
    out[base + (w + 12) * NCLS] = a3;
}

extern "C" void kernel_launch(void* const* d_in, const int* in_sizes, int n_in,
                              void* d_out, int out_size, void* d_ws, size_t ws_size,
                              hipStream_t stream)
{
    const float* x        = (const float*)d_in[0];
    const int*   ei       = (const int*)  d_in[1];
    const float* W_in     = (const float*)d_in[2];
    const float* b_in     = (const float*)d_in[3];
    const float* W_layers = (const float*)d_in[4];
    const float* b_layers = (const float*)d_in[5];
    const float* W_cls    = (const float*)d_in[6];
    const float* b_cls    = (const float*)d_in[7];
    float* out = (float*)d_out;

    // ws: two 12.8 MB bf16 node-feature buffers (ping-pong)
    unsigned short* H0 = (unsigned short*)d_ws;
    unsigned short* H1 = H0 + (size_t)N_NODES * HID;

    // build scratch lives in the x input buffer (51.2 MB = 12.8M ints), used
    // only AFTER k_in_gemm consumed x (stream-ordered). Harness restores
    // inputs from pristine before every launch, so clobbering is sanctioned.
    int* xb        = (int*)d_in[0];
    int* pairs     = xb;                          // 1.6M ints
    int* srcs      = xb + E_NUM;                  // 1.6M ints
    int* row_start = xb + 2 * E_NUM;              // 100001 ints
    int* hist      = xb + 2 * E_NUM + 100064;     // 782
    int* base      = hist + 1024;                 // 783
    int* cursor    = base + 1024;                 // 782

    const int gemm_blocks = N_NODES / 16;         // 6250

    k_in_gemm  <<<gemm_blocks, 256, 0, stream>>>(x, W_in, b_in, H0);

    k_zero_hist<<<4, 256, 0, stream>>>(hist);
    k_hist     <<<NTILE, 256, 0, stream>>>(ei, hist);
    k_scan     <<<1, 1024, 0, stream>>>(hist, base, cursor);
    k_part     <<<NTILE, 256, 0, stream>>>(ei, cursor, pairs);
    k_bsort    <<<NBUCK, 256, 0, stream>>>(base, pairs, srcs, row_start);

    unsigned short* Hi = H0; unsigned short* Ho = H1;
    for (int i = 0; i < 3; ++i) {
        k_gather_gemm<<<gemm_blocks, 256, 0, stream>>>(
            row_start, srcs, Hi,
            W_layers + (size_t)i * HID * HID, b_layers + (size_t)i * HID, Ho);
        unsigned short* tmp = Hi; Hi = Ho; Ho = tmp;
    }
    k_cls<<<gemm_blocks, 256, 0, stream>>>(W_cls, b_cls, Hi, out);
}